// Round 1
// baseline (950.243 us; speedup 1.0000x reference)
//
#include <hip/hip_runtime.h>

#define HW 4096
#define NC 64
#define NB 8
#define EPS 1e-5f

// ---------------------------------------------------------------------------
// Kernel A: fused 1x1-conv + BN (+ saliency mask for Q)
//   Qt [B][HW][C]  (query, masked)      -- row-major over C for S-tile A-loads
//   Kc [B][C][HW]  (key)                -- row-major over HW for S-tile B-loads
//   Vc [B][C][HW]  (value)              -- row-major over HW for PV loads
// ---------------------------------------------------------------------------
__global__ __launch_bounds__(256) void qkv_kernel(
    const float* __restrict__ x, const float* __restrict__ sal,
    const float* __restrict__ wq, const float* __restrict__ bq,
    const float* __restrict__ gq, const float* __restrict__ beq,
    const float* __restrict__ wk, const float* __restrict__ bk,
    const float* __restrict__ gk, const float* __restrict__ bek,
    const float* __restrict__ wv, const float* __restrict__ bv,
    const float* __restrict__ gv, const float* __restrict__ bev,
    float* __restrict__ Qt, float* __restrict__ Kc, float* __restrict__ Vc)
{
    __shared__ float w_lds[3][64][64];
    __shared__ float sc_lds[3][64];
    __shared__ float bb_lds[3][64];
    __shared__ float x_lds[64][68];

    const int t = threadIdx.x;
    const int b = blockIdx.x >> 6;
    const int p0 = (blockIdx.x & 63) * 64;

    if (t < 192) {
        int m = t >> 6, o = t & 63;
        const float* g  = (m == 0) ? gq  : (m == 1) ? gk  : gv;
        const float* be = (m == 0) ? beq : (m == 1) ? bek : bev;
        const float* bi = (m == 0) ? bq  : (m == 1) ? bk  : bv;
        float s = g[o] * rsqrtf(1.0f + EPS);
        sc_lds[m][o] = s;
        bb_lds[m][o] = bi[o] * s + be[o];
    }
    __syncthreads();

    // scaled weights into LDS (12288 floats)
    for (int rep = 0; rep < 12; ++rep) {
        int idx = (rep * 256 + t) * 4;
        int m = idx >> 12;
        int r = idx & 4095;
        int o = r >> 6;
        const float* w = (m == 0) ? wq : (m == 1) ? wk : wv;
        float4 v4 = *reinterpret_cast<const float4*>(w + r);
        float s = sc_lds[m][o];
        int c0 = r & 63;
        w_lds[m][o][c0 + 0] = v4.x * s;
        w_lds[m][o][c0 + 1] = v4.y * s;
        w_lds[m][o][c0 + 2] = v4.z * s;
        w_lds[m][o][c0 + 3] = v4.w * s;
    }
    // x tile [64c][64p]
    for (int rep = 0; rep < 4; ++rep) {
        int idx = (rep * 256 + t) * 4;
        int c = idx >> 6, p = idx & 63;
        float4 v4 = *reinterpret_cast<const float4*>(
            x + (((size_t)(b * 64 + c)) << 12) + p0 + p);
        *reinterpret_cast<float4*>(&x_lds[c][p]) = v4;
    }
    __syncthreads();

    const int p = t & 63, og = t >> 6;
    float xr[64];
#pragma unroll
    for (int c = 0; c < 64; ++c) xr[c] = x_lds[c][p];
    const float mask = sal[(((size_t)b) << 12) + p0 + p];

#pragma unroll
    for (int m = 0; m < 3; ++m) {
        float outv[16];
#pragma unroll
        for (int oo = 0; oo < 16; ++oo) {
            int o = og * 16 + oo;
            float acc = bb_lds[m][o];
#pragma unroll
            for (int c = 0; c < 64; ++c) acc += w_lds[m][o][c] * xr[c];
            outv[oo] = acc;
        }
        if (m == 0) {
            size_t base = ((((size_t)b) << 12) + p0 + p) * 64 + og * 16;
#pragma unroll
            for (int oo = 0; oo < 16; ++oo) Qt[base + oo] = outv[oo] * mask;
        } else {
            float* dst = (m == 1) ? Kc : Vc;
#pragma unroll
            for (int oo = 0; oo < 16; ++oo) {
                int o = og * 16 + oo;
                dst[(((size_t)(b * 64 + o)) << 12) + p0 + p] = outv[oo];
            }
        }
    }
}

// ---------------------------------------------------------------------------
// Kernel B: inv_l[b][i] = 1 / sum_j exp( sum_c Qt[i][c] * Kc[c][j] )
// block = one (b, 64-row i-tile); loop over 64-column j-chunks
// ---------------------------------------------------------------------------
__global__ __launch_bounds__(256) void rowsum_kernel(
    const float* __restrict__ Qt, const float* __restrict__ Kc,
    float* __restrict__ inv_l)
{
    __shared__ float q_lds[64][68];
    __shared__ float k_lds[64][68];

    const int t = threadIdx.x;
    const int b = blockIdx.x >> 6;
    const int i0 = (blockIdx.x & 63) * 64;

    for (int rep = 0; rep < 4; ++rep) {
        int idx = (rep * 256 + t) * 4;
        int i = idx >> 6, c = idx & 63;
        float4 v4 = *reinterpret_cast<const float4*>(
            Qt + ((((size_t)b) << 12) + i0 + i) * 64 + c);
        *reinterpret_cast<float4*>(&q_lds[i][c]) = v4;
    }

    const int jt = t & 15, it = t >> 4;
    const int i4 = it * 4, j4 = jt * 4;
    float lp[4] = {0.f, 0.f, 0.f, 0.f};

    for (int ch = 0; ch < 64; ++ch) {
        __syncthreads();
        for (int rep = 0; rep < 4; ++rep) {
            int idx = (rep * 256 + t) * 4;
            int c = idx >> 6, j = idx & 63;
            float4 v4 = *reinterpret_cast<const float4*>(
                Kc + (((size_t)(b * 64 + c)) << 12) + ch * 64 + j);
            *reinterpret_cast<float4*>(&k_lds[c][j]) = v4;
        }
        __syncthreads();

        float sacc[4][4];
#pragma unroll
        for (int d = 0; d < 4; ++d)
#pragma unroll
            for (int e = 0; e < 4; ++e) sacc[d][e] = 0.f;

#pragma unroll 4
        for (int c = 0; c < 64; c += 4) {
            float4 qr[4], kr[4];
#pragma unroll
            for (int d = 0; d < 4; ++d)
                qr[d] = *reinterpret_cast<const float4*>(&q_lds[i4 + d][c]);
#pragma unroll
            for (int cc = 0; cc < 4; ++cc)
                kr[cc] = *reinterpret_cast<const float4*>(&k_lds[c + cc][j4]);
#pragma unroll
            for (int d = 0; d < 4; ++d) {
                sacc[d][0] += qr[d].x * kr[0].x + qr[d].y * kr[1].x + qr[d].z * kr[2].x + qr[d].w * kr[3].x;
                sacc[d][1] += qr[d].x * kr[0].y + qr[d].y * kr[1].y + qr[d].z * kr[2].y + qr[d].w * kr[3].y;
                sacc[d][2] += qr[d].x * kr[0].z + qr[d].y * kr[1].z + qr[d].z * kr[2].z + qr[d].w * kr[3].z;
                sacc[d][3] += qr[d].x * kr[0].w + qr[d].y * kr[1].w + qr[d].z * kr[2].w + qr[d].w * kr[3].w;
            }
        }
#pragma unroll
        for (int d = 0; d < 4; ++d)
#pragma unroll
            for (int e = 0; e < 4; ++e) lp[d] += __expf(sacc[d][e]);
    }

#pragma unroll
    for (int off = 1; off < 16; off <<= 1)
#pragma unroll
        for (int d = 0; d < 4; ++d) lp[d] += __shfl_xor(lp[d], off);

    if (jt == 0) {
#pragma unroll
        for (int d = 0; d < 4; ++d)
            inv_l[(((size_t)b) << 12) + i0 + i4 + d] = 1.0f / lp[d];
    }
}

// ---------------------------------------------------------------------------
// Kernel C: enhanced[c][j] = sum_i Vc[c][i] * exp(s[i][j]) * inv_l[i],
//           out = (enhanced + x) * scale_o + beta_o
// block = one (b, 64-column j-tile); loop over 64-row i-chunks
// ---------------------------------------------------------------------------
__global__ __launch_bounds__(256) void attnout_kernel(
    const float* __restrict__ Qt, const float* __restrict__ Kc,
    const float* __restrict__ Vc, const float* __restrict__ inv_l,
    const float* __restrict__ x, const float* __restrict__ go,
    const float* __restrict__ beo, float* __restrict__ out)
{
    __shared__ float k_lds[64][68];
    __shared__ float q_lds[64][68];
    __shared__ float v_lds[64][65];
    __shared__ float p_lds[64][68];
    __shared__ float li_lds[64];

    const int t = threadIdx.x;
    const int b = blockIdx.x >> 6;
    const int j0 = (blockIdx.x & 63) * 64;

    // fixed K tile [64c][64j]
    for (int rep = 0; rep < 4; ++rep) {
        int idx = (rep * 256 + t) * 4;
        int c = idx >> 6, j = idx & 63;
        float4 v4 = *reinterpret_cast<const float4*>(
            Kc + (((size_t)(b * 64 + c)) << 12) + j0 + j);
        *reinterpret_cast<float4*>(&k_lds[c][j]) = v4;
    }

    const int jt = t & 15, it = t >> 4;
    const int i4 = it * 4, j4 = jt * 4;
    const int cph = t & 63, jg = t >> 6;   // phase-2 mapping
    float acc[16];
#pragma unroll
    for (int e = 0; e < 16; ++e) acc[e] = 0.f;

    for (int ch = 0; ch < 64; ++ch) {
        const int ic0 = ch * 64;
        __syncthreads();
        // q chunk [64i][64c]
        for (int rep = 0; rep < 4; ++rep) {
            int idx = (rep * 256 + t) * 4;
            int i = idx >> 6, c = idx & 63;
            float4 v4 = *reinterpret_cast<const float4*>(
                Qt + ((((size_t)b) << 12) + ic0 + i) * 64 + c);
            *reinterpret_cast<float4*>(&q_lds[i][c]) = v4;
        }
        // v chunk [64c][64i], stride-65 (bank-conflict-free phase-2 reads)
        for (int rep = 0; rep < 4; ++rep) {
            int idx = (rep * 256 + t) * 4;
            int c = idx >> 6, i = idx & 63;
            float4 v4 = *reinterpret_cast<const float4*>(
                Vc + (((size_t)(b * 64 + c)) << 12) + ic0 + i);
            v_lds[c][i + 0] = v4.x;
            v_lds[c][i + 1] = v4.y;
            v_lds[c][i + 2] = v4.z;
            v_lds[c][i + 3] = v4.w;
        }
        if (t < 64) li_lds[t] = inv_l[(((size_t)b) << 12) + ic0 + t];
        __syncthreads();

        // phase 1: S tile -> P = exp(S)*inv_l -> LDS
        float sacc[4][4];
#pragma unroll
        for (int d = 0; d < 4; ++d)
#pragma unroll
            for (int e = 0; e < 4; ++e) sacc[d][e] = 0.f;

#pragma unroll 4
        for (int c = 0; c < 64; c += 4) {
            float4 qr[4], kr[4];
#pragma unroll
            for (int d = 0; d < 4; ++d)
                qr[d] = *reinterpret_cast<const float4*>(&q_lds[i4 + d][c]);
#pragma unroll
            for (int cc = 0; cc < 4; ++cc)
                kr[cc] = *reinterpret_cast<const float4*>(&k_lds[c + cc][j4]);
#pragma unroll
            for (int d = 0; d < 4; ++d) {
                sacc[d][0] += qr[d].x * kr[0].x + qr[d].y * kr[1].x + qr[d].z * kr[2].x + qr[d].w * kr[3].x;
                sacc[d][1] += qr[d].x * kr[0].y + qr[d].y * kr[1].y + qr[d].z * kr[2].y + qr[d].w * kr[3].y;
                sacc[d][2] += qr[d].x * kr[0].z + qr[d].y * kr[1].z + qr[d].z * kr[2].z + qr[d].w * kr[3].z;
                sacc[d][3] += qr[d].x * kr[0].w + qr[d].y * kr[1].w + qr[d].z * kr[2].w + qr[d].w * kr[3].w;
            }
        }
#pragma unroll
        for (int d = 0; d < 4; ++d) {
            float li = li_lds[i4 + d];
            float4 pv;
            pv.x = __expf(sacc[d][0]) * li;
            pv.y = __expf(sacc[d][1]) * li;
            pv.z = __expf(sacc[d][2]) * li;
            pv.w = __expf(sacc[d][3]) * li;
            *reinterpret_cast<float4*>(&p_lds[i4 + d][j4]) = pv;
        }
        __syncthreads();

        // phase 2: acc[c][16 j] += v[c][i] * P[i][j]
        const int jg16 = jg * 16;
#pragma unroll 8
        for (int i = 0; i < 64; ++i) {
            float vv = v_lds[cph][i];
            float4 p0 = *reinterpret_cast<const float4*>(&p_lds[i][jg16 + 0]);
            float4 p1 = *reinterpret_cast<const float4*>(&p_lds[i][jg16 + 4]);
            float4 p2 = *reinterpret_cast<const float4*>(&p_lds[i][jg16 + 8]);
            float4 p3 = *reinterpret_cast<const float4*>(&p_lds[i][jg16 + 12]);
            acc[0]  += vv * p0.x; acc[1]  += vv * p0.y; acc[2]  += vv * p0.z; acc[3]  += vv * p0.w;
            acc[4]  += vv * p1.x; acc[5]  += vv * p1.y; acc[6]  += vv * p1.z; acc[7]  += vv * p1.w;
            acc[8]  += vv * p2.x; acc[9]  += vv * p2.y; acc[10] += vv * p2.z; acc[11] += vv * p2.w;
            acc[12] += vv * p3.x; acc[13] += vv * p3.y; acc[14] += vv * p3.z; acc[15] += vv * p3.w;
        }
    }

    // epilogue: residual + BN_o
    const float sc = go[cph] * rsqrtf(1.0f + EPS);
    const float bb = beo[cph];
    size_t base = (((size_t)(b * 64 + cph)) << 12) + j0 + jg * 16;
#pragma unroll
    for (int q = 0; q < 4; ++q) {
        float4 xv = *reinterpret_cast<const float4*>(x + base + q * 4);
        float4 ov;
        ov.x = (acc[q * 4 + 0] + xv.x) * sc + bb;
        ov.y = (acc[q * 4 + 1] + xv.y) * sc + bb;
        ov.z = (acc[q * 4 + 2] + xv.z) * sc + bb;
        ov.w = (acc[q * 4 + 3] + xv.w) * sc + bb;
        *reinterpret_cast<float4*>(out + base + q * 4) = ov;
    }
}

extern "C" void kernel_launch(void* const* d_in, const int* in_sizes, int n_in,
                              void* d_out, int out_size, void* d_ws, size_t ws_size,
                              hipStream_t stream)
{
    (void)in_sizes; (void)n_in; (void)out_size; (void)ws_size;
    const float* x   = (const float*)d_in[0];
    const float* sal = (const float*)d_in[1];
    const float* wq  = (const float*)d_in[2];  const float* bq  = (const float*)d_in[3];
    const float* gq  = (const float*)d_in[4];  const float* beq = (const float*)d_in[5];
    const float* wk  = (const float*)d_in[6];  const float* bk  = (const float*)d_in[7];
    const float* gk  = (const float*)d_in[8];  const float* bek = (const float*)d_in[9];
    const float* wv  = (const float*)d_in[10]; const float* bv  = (const float*)d_in[11];
    const float* gv  = (const float*)d_in[12]; const float* bev = (const float*)d_in[13];
    const float* go  = (const float*)d_in[14]; const float* beo = (const float*)d_in[15];
    float* out = (float*)d_out;

    float* ws = (float*)d_ws;
    float* Qt = ws;                 // 2,097,152 floats
    float* Kc = ws + 2097152;       // 2,097,152
    float* Vc = ws + 4194304;       // 2,097,152
    float* il = ws + 6291456;       // 32,768

    qkv_kernel<<<512, 256, 0, stream>>>(x, sal, wq, bq, gq, beq,
                                        wk, bk, gk, bek, wv, bv, gv, bev,
                                        Qt, Kc, Vc);
    rowsum_kernel<<<512, 256, 0, stream>>>(Qt, Kc, il);
    attnout_kernel<<<512, 256, 0, stream>>>(Qt, Kc, Vc, il, x, go, beo, out);
}

// Round 3
// 283.713 us; speedup vs baseline: 3.3493x; 3.3493x over previous
//
#include <hip/hip_runtime.h>

#define EPS 1e-5f

typedef __attribute__((ext_vector_type(8)))  short    s8b;    // 8 bf16 held as shorts (4 VGPR)
typedef __attribute__((ext_vector_type(16))) float    f32x16; // 32x32 MFMA acc
typedef __attribute__((ext_vector_type(4)))  float    f32x4;
typedef __attribute__((ext_vector_type(4)))  unsigned u32x4;

__device__ __forceinline__ unsigned cvt_pk_bf16(float lo, float hi) {
    unsigned r;
    asm("v_cvt_pk_bf16_f32 %0, %1, %2" : "=v"(r) : "v"(lo), "v"(hi));
    return r;
}
__device__ __forceinline__ void permswap(unsigned &a, unsigned &b) {
    asm("v_permlane32_swap_b32 %0, %1" : "+v"(a), "+v"(b));
}
union PackAB { u32x4 u; s8b s; };

__device__ __forceinline__ unsigned short f2bf(float f) {
    union { float f; unsigned u; } v; v.f = f;
    unsigned r = v.u + 0x7FFFu + ((v.u >> 16) & 1u);
    return (unsigned short)(r >> 16);
}

// ---------------------------------------------------------------------------
// Kernel A: fused 1x1-conv + BN (+ saliency mask for Q), bf16 outputs
//   Qb [B][HW][C]  (masked query, row-major C)
//   Kb [B][HW][C]  (key transposed,  row-major C)
//   Vb [B][C][HW]  (value, row-major HW)
// ---------------------------------------------------------------------------
__global__ __launch_bounds__(256) void qkv_kernel(
    const float* __restrict__ x, const float* __restrict__ sal,
    const float* __restrict__ wq, const float* __restrict__ bq,
    const float* __restrict__ gq, const float* __restrict__ beq,
    const float* __restrict__ wk, const float* __restrict__ bk,
    const float* __restrict__ gk, const float* __restrict__ bek,
    const float* __restrict__ wv, const float* __restrict__ bv,
    const float* __restrict__ gv, const float* __restrict__ bev,
    short* __restrict__ Qb, short* __restrict__ Kb, short* __restrict__ Vb)
{
    __shared__ float w_lds[3][64][64];
    __shared__ float sc_lds[3][64];
    __shared__ float bb_lds[3][64];
    __shared__ float x_lds[64][68];

    const int t = threadIdx.x;
    const int b = blockIdx.x >> 6;
    const int p0 = (blockIdx.x & 63) * 64;

    if (t < 192) {
        int m = t >> 6, o = t & 63;
        const float* g  = (m == 0) ? gq  : (m == 1) ? gk  : gv;
        const float* be = (m == 0) ? beq : (m == 1) ? bek : bev;
        const float* bi = (m == 0) ? bq  : (m == 1) ? bk  : bv;
        float s = g[o] * rsqrtf(1.0f + EPS);
        sc_lds[m][o] = s;
        bb_lds[m][o] = bi[o] * s + be[o];
    }
    __syncthreads();

    for (int rep = 0; rep < 12; ++rep) {
        int idx = (rep * 256 + t) * 4;
        int m = idx >> 12;
        int r = idx & 4095;
        int o = r >> 6;
        const float* w = (m == 0) ? wq : (m == 1) ? wk : wv;
        float4 v4 = *reinterpret_cast<const float4*>(w + r);
        float s = sc_lds[m][o];
        int c0 = r & 63;
        w_lds[m][o][c0 + 0] = v4.x * s;
        w_lds[m][o][c0 + 1] = v4.y * s;
        w_lds[m][o][c0 + 2] = v4.z * s;
        w_lds[m][o][c0 + 3] = v4.w * s;
    }
    for (int rep = 0; rep < 4; ++rep) {
        int idx = (rep * 256 + t) * 4;
        int c = idx >> 6, p = idx & 63;
        float4 v4 = *reinterpret_cast<const float4*>(
            x + (((size_t)(b * 64 + c)) << 12) + p0 + p);
        *reinterpret_cast<float4*>(&x_lds[c][p]) = v4;
    }
    __syncthreads();

    const int p = t & 63, og = t >> 6;
    float xr[64];
#pragma unroll
    for (int c = 0; c < 64; ++c) xr[c] = x_lds[c][p];
    const float mask = sal[(((size_t)b) << 12) + p0 + p];

#pragma unroll
    for (int m = 0; m < 3; ++m) {
        float outv[16];
#pragma unroll
        for (int oo = 0; oo < 16; ++oo) {
            int o = og * 16 + oo;
            float acc = bb_lds[m][o];
#pragma unroll
            for (int c = 0; c < 64; ++c) acc += w_lds[m][o][c] * xr[c];
            outv[oo] = acc;
        }
        if (m < 2) {
            if (m == 0) {
#pragma unroll
                for (int oo = 0; oo < 16; ++oo) outv[oo] *= mask;
            }
            short* dst = (m == 0) ? Qb : Kb;
            size_t base = ((((size_t)b) << 12) + p0 + p) * 64 + og * 16;
            u32x4 pk0, pk1;
            pk0.x = cvt_pk_bf16(outv[0],  outv[1]);
            pk0.y = cvt_pk_bf16(outv[2],  outv[3]);
            pk0.z = cvt_pk_bf16(outv[4],  outv[5]);
            pk0.w = cvt_pk_bf16(outv[6],  outv[7]);
            pk1.x = cvt_pk_bf16(outv[8],  outv[9]);
            pk1.y = cvt_pk_bf16(outv[10], outv[11]);
            pk1.z = cvt_pk_bf16(outv[12], outv[13]);
            pk1.w = cvt_pk_bf16(outv[14], outv[15]);
            *reinterpret_cast<u32x4*>(dst + base)     = pk0;
            *reinterpret_cast<u32x4*>(dst + base + 8) = pk1;
        } else {
#pragma unroll
            for (int oo = 0; oo < 16; ++oo) {
                int o = og * 16 + oo;
                Vb[(((size_t)(b * 64 + o)) << 12) + p0 + p] =
                    (short)f2bf(outv[oo]);
            }
        }
    }
}

// ---------------------------------------------------------------------------
// Kernel B (MFMA): inv_l[b][i] = 1 / sum_j exp(S[i][j])
// block = (b, 64-row i-tile); 4 waves (wr = i-half, wc = j-half); Q frags in
// registers for the whole block, K frags streamed from global.
// ---------------------------------------------------------------------------
__global__ __launch_bounds__(256) void rowsum_kernel(
    const short* __restrict__ Qb, const short* __restrict__ Kb,
    float* __restrict__ inv_l)
{
    __shared__ float part[2][64];

    const int t = threadIdx.x;
    const int b = blockIdx.x >> 6;
    const int i0 = (blockIdx.x & 63) * 64;
    const int wave = t >> 6, lane = t & 63;
    const int wr = wave >> 1, wc = wave & 1;
    const int l31 = lane & 31, hi = lane >> 5;

    // Q A-fragments (fixed for the block): row i0+wr*32+l31, k = 16s+8hi..+8
    const short* qp = Qb + ((size_t)b * 4096 + i0 + wr * 32 + l31) * 64 + hi * 8;
    s8b qf[4];
#pragma unroll
    for (int s = 0; s < 4; ++s)
        qf[s] = *reinterpret_cast<const s8b*>(qp + s * 16);

    float lsum[16];
#pragma unroll
    for (int r = 0; r < 16; ++r) lsum[r] = 0.f;

    for (int jc = 0; jc < 4096; jc += 64) {
        const short* kp = Kb + ((size_t)b * 4096 + jc + wc * 32 + l31) * 64 + hi * 8;
        s8b kf[4];
#pragma unroll
        for (int s = 0; s < 4; ++s)
            kf[s] = *reinterpret_cast<const s8b*>(kp + s * 16);
        f32x16 sacc = {0.f};
#pragma unroll
        for (int r = 0; r < 16; ++r) sacc[r] = 0.f;
#pragma unroll
        for (int s = 0; s < 4; ++s)
            sacc = __builtin_amdgcn_mfma_f32_32x32x16_bf16(qf[s], kf[s], sacc, 0, 0, 0);
#pragma unroll
        for (int r = 0; r < 16; ++r) lsum[r] += __expf(sacc[r]);
    }

    // butterfly over the 32 lanes of each hi-half (j reduction)
#pragma unroll
    for (int off = 1; off < 32; off <<= 1)
#pragma unroll
        for (int r = 0; r < 16; ++r) lsum[r] += __shfl_xor(lsum[r], off);

    if (l31 == 0) {
#pragma unroll
        for (int r = 0; r < 16; ++r) {
            int iloc = wr * 32 + (r & 3) + 8 * (r >> 2) + 4 * hi;
            part[wc][iloc] = lsum[r];
        }
    }
    __syncthreads();
    if (t < 64)
        inv_l[(((size_t)b) << 12) + i0 + t] = 1.0f / (part[0][t] + part[1][t]);
}

// ---------------------------------------------------------------------------
// Kernel C (MFMA): out = BN_o( V @ softmax + x )
// block = (b, 64-col j-tile); wave (wr = i-half partial, wc = j-half).
// K frags in registers; Q/V frags streamed from global (L2); P repacked
// in-register (cvt_pk + permlane32_swap); PV computed transposed D[j][c].
// ---------------------------------------------------------------------------
__global__ __launch_bounds__(256) void attnout_kernel(
    const short* __restrict__ Qb, const short* __restrict__ Kb,
    const short* __restrict__ Vb, const float* __restrict__ inv_l,
    const float* __restrict__ x, const float* __restrict__ go,
    const float* __restrict__ beo, float* __restrict__ out)
{
    __shared__ float li_sh[4096];
    __shared__ float red[2][64][68];   // wr=1 partials, per wc

    const int t = threadIdx.x;
    const int b = blockIdx.x >> 6;
    const int j0 = (blockIdx.x & 63) * 64;
    const int wave = t >> 6, lane = t & 63;
    const int wr = wave >> 1, wc = wave & 1;
    const int l31 = lane & 31, hi = lane >> 5;

    // stage the whole batch's inv_l (16 KB)
    for (int rep = 0; rep < 4; ++rep) {
        int idx = (rep * 256 + t) * 4;
        *reinterpret_cast<f32x4*>(&li_sh[idx]) =
            *reinterpret_cast<const f32x4*>(inv_l + (((size_t)b) << 12) + idx);
    }

    // K B-fragments (fixed for the block): col j = j0+wc*32+l31, k = c
    const short* kp = Kb + ((size_t)b * 4096 + j0 + wc * 32 + l31) * 64 + hi * 8;
    s8b kf[4];
#pragma unroll
    for (int s = 0; s < 4; ++s)
        kf[s] = *reinterpret_cast<const s8b*>(kp + s * 16);
    __syncthreads();

    f32x16 acc0, acc1;
#pragma unroll
    for (int r = 0; r < 16; ++r) { acc0[r] = 0.f; acc1[r] = 0.f; }

    const size_t qrow0 = (size_t)b * 4096 * 64;       // elements
    const size_t vrow0 = (size_t)b * 64 * 4096;

    for (int ic0 = 0; ic0 < 4096; ic0 += 64) {
        // ---- S = Q K  (wave's 32i x 32j quadrant, K folded over 4 k-steps)
        const short* qp = Qb + qrow0 + (size_t)(ic0 + wr * 32 + l31) * 64 + hi * 8;
        s8b qf[4];
#pragma unroll
        for (int s = 0; s < 4; ++s)
            qf[s] = *reinterpret_cast<const s8b*>(qp + s * 16);

        // V B-fragments for this wave's i-slice: B[k=i][col=c]
        s8b vf[2][2];
#pragma unroll
        for (int s2 = 0; s2 < 2; ++s2)
#pragma unroll
            for (int nf = 0; nf < 2; ++nf)
                vf[s2][nf] = *reinterpret_cast<const s8b*>(
                    Vb + vrow0 + (size_t)(nf * 32 + l31) * 4096
                       + ic0 + wr * 32 + s2 * 16 + hi * 8);

        f32x16 sacc;
#pragma unroll
        for (int r = 0; r < 16; ++r) sacc[r] = 0.f;
#pragma unroll
        for (int s = 0; s < 4; ++s)
            sacc = __builtin_amdgcn_mfma_f32_32x32x16_bf16(qf[s], kf[s], sacc, 0, 0, 0);

        // ---- P = exp(S) * inv_l[i]   (i = ic0 + wr*32 + (r&3)+8*(r>>2)+4*hi)
        float p[16];
        const int ibase = ic0 + wr * 32 + 4 * hi;
#pragma unroll
        for (int g = 0; g < 4; ++g) {
            f32x4 li = *reinterpret_cast<const f32x4*>(&li_sh[ibase + 8 * g]);
#pragma unroll
            for (int q = 0; q < 4; ++q)
                p[g * 4 + q] = __expf(sacc[g * 4 + q]) * li[q];
        }

        // ---- repack P rows -> bf16 A-fragments (k = i), two 16-i steps
        unsigned a0 = cvt_pk_bf16(p[0],  p[1]);
        unsigned a1 = cvt_pk_bf16(p[2],  p[3]);
        unsigned a2 = cvt_pk_bf16(p[4],  p[5]);
        unsigned a3 = cvt_pk_bf16(p[6],  p[7]);
        unsigned b0 = cvt_pk_bf16(p[8],  p[9]);
        unsigned b1 = cvt_pk_bf16(p[10], p[11]);
        unsigned b2 = cvt_pk_bf16(p[12], p[13]);
        unsigned b3 = cvt_pk_bf16(p[14], p[15]);
        permswap(a0, a2); permswap(a1, a3);
        permswap(b0, b2); permswap(b1, b3);
        PackAB pa0, pa1;
        pa0.u.x = a0; pa0.u.y = a1; pa0.u.z = a2; pa0.u.w = a3;
        pa1.u.x = b0; pa1.u.y = b1; pa1.u.z = b2; pa1.u.w = b3;

        // ---- PV (transposed): D[j][c] += P^T[j][i] * V^T[i][c]
        acc0 = __builtin_amdgcn_mfma_f32_32x32x16_bf16(pa0.s, vf[0][0], acc0, 0, 0, 0);
        acc1 = __builtin_amdgcn_mfma_f32_32x32x16_bf16(pa0.s, vf[0][1], acc1, 0, 0, 0);
        acc0 = __builtin_amdgcn_mfma_f32_32x32x16_bf16(pa1.s, vf[1][0], acc0, 0, 0, 0);
        acc1 = __builtin_amdgcn_mfma_f32_32x32x16_bf16(pa1.s, vf[1][1], acc1, 0, 0, 0);
    }

    // ---- cross-wave combine (wr=1 partial -> LDS, wr=0 adds + epilogue)
    if (wr == 1) {
#pragma unroll
        for (int nf = 0; nf < 2; ++nf) {
            const f32x16& A = nf ? acc1 : acc0;
            int c = nf * 32 + l31;
#pragma unroll
            for (int g = 0; g < 4; ++g) {
                f32x4 v;
                v.x = A[g * 4 + 0]; v.y = A[g * 4 + 1];
                v.z = A[g * 4 + 2]; v.w = A[g * 4 + 3];
                *reinterpret_cast<f32x4*>(&red[wc][c][g * 8 + 4 * hi]) = v;
            }
        }
    }
    __syncthreads();
    if (wr == 0) {
#pragma unroll
        for (int nf = 0; nf < 2; ++nf) {
            const f32x16& A = nf ? acc1 : acc0;
            int c = nf * 32 + l31;
            const float sc = go[c] * rsqrtf(1.0f + EPS);
            const float bb = beo[c];
            size_t rowb = (((size_t)(b * 64 + c)) << 12) + j0 + wc * 32;
#pragma unroll
            for (int g = 0; g < 4; ++g) {
                int jl = g * 8 + 4 * hi;
                f32x4 prt = *reinterpret_cast<const f32x4*>(&red[wc][c][jl]);
                f32x4 xv  = *reinterpret_cast<const f32x4*>(x + rowb + jl);
                f32x4 ov;
                ov.x = (A[g * 4 + 0] + prt.x + xv.x) * sc + bb;
                ov.y = (A[g * 4 + 1] + prt.y + xv.y) * sc + bb;
                ov.z = (A[g * 4 + 2] + prt.z + xv.z) * sc + bb;
                ov.w = (A[g * 4 + 3] + prt.w + xv.w) * sc + bb;
                *reinterpret_cast<f32x4*>(out + rowb + jl) = ov;
            }
        }
    }
}

extern "C" void kernel_launch(void* const* d_in, const int* in_sizes, int n_in,
                              void* d_out, int out_size, void* d_ws, size_t ws_size,
                              hipStream_t stream)
{
    (void)in_sizes; (void)n_in; (void)out_size; (void)ws_size;
    const float* x   = (const float*)d_in[0];
    const float* sal = (const float*)d_in[1];
    const float* wq  = (const float*)d_in[2];  const float* bq  = (const float*)d_in[3];
    const float* gq  = (const float*)d_in[4];  const float* beq = (const float*)d_in[5];
    const float* gk  = (const float*)d_in[8];  const float* bek = (const float*)d_in[9];
    const float* wk  = (const float*)d_in[6];  const float* bk  = (const float*)d_in[7];
    const float* wv  = (const float*)d_in[10]; const float* bv  = (const float*)d_in[11];
    const float* gv  = (const float*)d_in[12]; const float* bev = (const float*)d_in[13];
    const float* go  = (const float*)d_in[14]; const float* beo = (const float*)d_in[15];
    float* out = (float*)d_out;

    short* ws = (short*)d_ws;
    short* Qb = ws;                     // 2,097,152 bf16
    short* Kb = ws + 2097152;           // 2,097,152 bf16
    short* Vb = ws + 4194304;           // 2,097,152 bf16
    float* il = (float*)(ws + 6291456); // 32,768 f32

    qkv_kernel<<<512, 256, 0, stream>>>(x, sal, wq, bq, gq, beq,
                                        wk, bk, gk, bek, wv, bv, gv, bev,
                                        Qb, Kb, Vb);
    rowsum_kernel<<<512, 256, 0, stream>>>(Qb, Kb, il);
    attnout_kernel<<<512, 256, 0, stream>>>(Qb, Kb, Vb, il, x, go, beo, out);
}

// Round 4
// 188.905 us; speedup vs baseline: 5.0303x; 1.5019x over previous
//
#include <hip/hip_runtime.h>

#define EPS 1e-5f

typedef __attribute__((ext_vector_type(8)))  short    s8b;    // 8 bf16 (4 VGPR)
typedef __attribute__((ext_vector_type(16))) float    f32x16; // 32x32 MFMA acc
typedef __attribute__((ext_vector_type(4)))  float    f32x4;
typedef __attribute__((ext_vector_type(4)))  unsigned u32x4;

__device__ __forceinline__ unsigned cvt_pk_bf16(float lo, float hi) {
    unsigned r;
    asm("v_cvt_pk_bf16_f32 %0, %1, %2" : "=v"(r) : "v"(lo), "v"(hi));
    return r;
}
__device__ __forceinline__ void permswap(unsigned &a, unsigned &b) {
    asm("v_permlane32_swap_b32 %0, %1" : "+v"(a), "+v"(b));
}
union PackAB { u32x4 u; s8b s; };

__device__ __forceinline__ unsigned short f2bf(float f) {
    union { float f; unsigned u; } v; v.f = f;
    unsigned r = v.u + 0x7FFFu + ((v.u >> 16) & 1u);
    return (unsigned short)(r >> 16);
}

// Fragment-major layouts (element indices, bf16):
//  Qf/Kf: ((((b*128 + ib)*4 + s)*2 + hi)*32 + l)*8 + e    i/j = ib*32+l, k = s*16+hi*8+e
//  Vf:    ((((b*128 + ib)*2 + s2)*2 + hi)*64 + c)*8 + e   k=i = ib*32+s2*16+hi*8+e, col=c

// ---------------------------------------------------------------------------
// Kernel A: fused 1x1-conv + BN (+ saliency mask for Q) -> fragment-major bf16
// ---------------------------------------------------------------------------
__global__ __launch_bounds__(256) void qkv_kernel(
    const float* __restrict__ x, const float* __restrict__ sal,
    const float* __restrict__ wq, const float* __restrict__ bq,
    const float* __restrict__ gq, const float* __restrict__ beq,
    const float* __restrict__ wk, const float* __restrict__ bk,
    const float* __restrict__ gk, const float* __restrict__ bek,
    const float* __restrict__ wv, const float* __restrict__ bv,
    const float* __restrict__ gv, const float* __restrict__ bev,
    short* __restrict__ Qf, short* __restrict__ Kf, short* __restrict__ Vf)
{
    __shared__ float w_lds[3][64][64];
    __shared__ float sc_lds[3][64];
    __shared__ float bb_lds[3][64];
    __shared__ float x_lds[64][68];
    __shared__ short v_lds[64 * 64];   // XOR-swizzled transpose buffer

    const int t = threadIdx.x;
    const int b = blockIdx.x & 7;
    const int p0 = (blockIdx.x >> 3) * 64;

    if (t < 192) {
        int m = t >> 6, o = t & 63;
        const float* g  = (m == 0) ? gq  : (m == 1) ? gk  : gv;
        const float* be = (m == 0) ? beq : (m == 1) ? bek : bev;
        const float* bi = (m == 0) ? bq  : (m == 1) ? bk  : bv;
        float s = g[o] * rsqrtf(1.0f + EPS);
        sc_lds[m][o] = s;
        bb_lds[m][o] = bi[o] * s + be[o];
    }
    __syncthreads();

    for (int rep = 0; rep < 12; ++rep) {
        int idx = (rep * 256 + t) * 4;
        int m = idx >> 12;
        int r = idx & 4095;
        int o = r >> 6;
        const float* w = (m == 0) ? wq : (m == 1) ? wk : wv;
        float4 v4 = *reinterpret_cast<const float4*>(w + r);
        float s = sc_lds[m][o];
        int c0 = r & 63;
        w_lds[m][o][c0 + 0] = v4.x * s;
        w_lds[m][o][c0 + 1] = v4.y * s;
        w_lds[m][o][c0 + 2] = v4.z * s;
        w_lds[m][o][c0 + 3] = v4.w * s;
    }
    for (int rep = 0; rep < 4; ++rep) {
        int idx = (rep * 256 + t) * 4;
        int c = idx >> 6, p = idx & 63;
        float4 v4 = *reinterpret_cast<const float4*>(
            x + (((size_t)(b * 64 + c)) << 12) + p0 + p);
        *reinterpret_cast<float4*>(&x_lds[c][p]) = v4;
    }
    __syncthreads();

    const int p = t & 63, og = t >> 6;
    const int i = p0 + p;
    float xr[64];
#pragma unroll
    for (int c = 0; c < 64; ++c) xr[c] = x_lds[c][p];
    const float mask = sal[(((size_t)b) << 12) + i];

#pragma unroll
    for (int m = 0; m < 3; ++m) {
        float outv[16];
#pragma unroll
        for (int oo = 0; oo < 16; ++oo) {
            int o = og * 16 + oo;
            float acc = bb_lds[m][o];
#pragma unroll
            for (int c = 0; c < 64; ++c) acc += w_lds[m][o][c] * xr[c];
            outv[oo] = acc;
        }
        if (m < 2) {
            if (m == 0) {
#pragma unroll
                for (int oo = 0; oo < 16; ++oo) outv[oo] *= mask;
            }
            short* dst = (m == 0) ? Qf : Kf;
            // frag store: ib=i>>5, l=i&31, s=og, hi=oo>>3, e=oo&7
            size_t base =
                ((((size_t)(b * 128 + (i >> 5)) * 4 + og) * 2) * 32 + (i & 31)) * 8;
            u32x4 pk0, pk1;
            pk0.x = cvt_pk_bf16(outv[0],  outv[1]);
            pk0.y = cvt_pk_bf16(outv[2],  outv[3]);
            pk0.z = cvt_pk_bf16(outv[4],  outv[5]);
            pk0.w = cvt_pk_bf16(outv[6],  outv[7]);
            pk1.x = cvt_pk_bf16(outv[8],  outv[9]);
            pk1.y = cvt_pk_bf16(outv[10], outv[11]);
            pk1.z = cvt_pk_bf16(outv[12], outv[13]);
            pk1.w = cvt_pk_bf16(outv[14], outv[15]);
            *reinterpret_cast<u32x4*>(dst + base)       = pk0;   // hi=0
            *reinterpret_cast<u32x4*>(dst + base + 256) = pk1;   // hi=1
        } else {
            // V -> swizzled LDS transpose [c][p]
#pragma unroll
            for (int oo = 0; oo < 16; ++oo) {
                int c = og * 16 + oo;
                int sidx = (c * 64 + p) ^ ((c & 7) << 3);
                v_lds[sidx] = (short)f2bf(outv[oo]);
            }
        }
    }
    __syncthreads();

    // cooperative Vf write: tile = 4096 elements contiguous at (b*128 + p0/32)*2048
    const size_t vbase = (size_t)(b * 128 + (p0 >> 5)) * 2048;
#pragma unroll
    for (int r = 0; r < 2; ++r) {
        int f = r * 256 + t;             // chunk 0..511
        int c = f & 63;
        int iL = ((f >> 6) & 7) * 8;     // local i offset (mult of 8)
        int sidx = (c * 64 + iL) ^ ((c & 7) << 3);
        u32x4 val = *reinterpret_cast<const u32x4*>(&v_lds[sidx]);
        *reinterpret_cast<u32x4*>(Vf + vbase + (size_t)f * 8) = val;
    }
}

// ---------------------------------------------------------------------------
// Kernel B (MFMA): inv_l[b][i] = 1 / sum_j exp(S[i][j])
// block = (b, 32-row i-block); 4 waves j-split 4-way; coalesced frag loads.
// ---------------------------------------------------------------------------
__global__ __launch_bounds__(256, 4) void rowsum_kernel(
    const short* __restrict__ Qf, const short* __restrict__ Kf,
    float* __restrict__ inv_l)
{
    __shared__ float part[4][32];

    const int t = threadIdx.x;
    const int b = blockIdx.x & 7;
    const int it = blockIdx.x >> 3;          // i-block 0..127
    const int wave = t >> 6, lane = t & 63;
    const int l31 = lane & 31, hi = lane >> 5;

    const short* qp = Qf +
        ((((size_t)(b * 128 + it) * 4) * 2 + hi) * 32 + l31) * 8;
    s8b qf[4];
#pragma unroll
    for (int s = 0; s < 4; ++s)
        qf[s] = *reinterpret_cast<const s8b*>(qp + s * 512);

    float lsum[16];
#pragma unroll
    for (int r = 0; r < 16; ++r) lsum[r] = 0.f;

    for (int jb = wave; jb < 128; jb += 4) {
        const short* kp = Kf +
            ((((size_t)(b * 128 + jb) * 4) * 2 + hi) * 32 + l31) * 8;
        s8b kf[4];
#pragma unroll
        for (int s = 0; s < 4; ++s)
            kf[s] = *reinterpret_cast<const s8b*>(kp + s * 512);
        f32x16 sacc;
#pragma unroll
        for (int r = 0; r < 16; ++r) sacc[r] = 0.f;
#pragma unroll
        for (int s = 0; s < 4; ++s)
            sacc = __builtin_amdgcn_mfma_f32_32x32x16_bf16(qf[s], kf[s], sacc, 0, 0, 0);
#pragma unroll
        for (int r = 0; r < 16; ++r) lsum[r] += __expf(sacc[r]);
    }

#pragma unroll
    for (int off = 1; off < 32; off <<= 1)
#pragma unroll
        for (int r = 0; r < 16; ++r) lsum[r] += __shfl_xor(lsum[r], off);

    if (l31 == 0) {
#pragma unroll
        for (int r = 0; r < 16; ++r) {
            int iloc = (r & 3) + 8 * (r >> 2) + 4 * hi;
            part[wave][iloc] = lsum[r];
        }
    }
    __syncthreads();
    if (t < 32)
        inv_l[(((size_t)b) << 12) + it * 32 + t] =
            1.0f / (part[0][t] + part[1][t] + part[2][t] + part[3][t]);
}

// ---------------------------------------------------------------------------
// Kernel C (MFMA): out = BN_o( V @ softmax + x )
// block = (b, 64-col j-tile); 8 waves: wr=i-split(4) x wc=j-half(2).
// All main-loop loads are coalesced fragment loads; LDS tree-combine.
// ---------------------------------------------------------------------------
__global__ __launch_bounds__(512, 4) void attnout_kernel(
    const short* __restrict__ Qf, const short* __restrict__ Kf,
    const short* __restrict__ Vf, const float* __restrict__ inv_l,
    const float* __restrict__ x, const float* __restrict__ go,
    const float* __restrict__ beo, float* __restrict__ out)
{
    __shared__ float red[2][3][64][33];   // [wc][wr-1][c][j]

    const int t = threadIdx.x;
    const int b = blockIdx.x & 7;
    const int jt = blockIdx.x >> 3;        // 0..63  -> j0 = jt*64
    const int wave = t >> 6, lane = t & 63;
    const int wr = wave >> 1;              // 0..3 i-split
    const int wc = wave & 1;               // j-half
    const int l31 = lane & 31, hi = lane >> 5;

    // K B-frags fixed: j-block = jt*2 + wc
    const short* kp = Kf +
        ((((size_t)(b * 128 + jt * 2 + wc) * 4) * 2 + hi) * 32 + l31) * 8;
    s8b kf[4];
#pragma unroll
    for (int s = 0; s < 4; ++s)
        kf[s] = *reinterpret_cast<const s8b*>(kp + s * 512);

    f32x16 acc0, acc1;
#pragma unroll
    for (int r = 0; r < 16; ++r) { acc0[r] = 0.f; acc1[r] = 0.f; }

    const float* lip = inv_l + (((size_t)b) << 12);

    for (int ii = 0; ii < 32; ++ii) {
        const int ib = ii * 4 + wr;        // i-block 0..127
        const short* qp = Qf +
            ((((size_t)(b * 128 + ib) * 4) * 2 + hi) * 32 + l31) * 8;
        s8b qf[4];
#pragma unroll
        for (int s = 0; s < 4; ++s)
            qf[s] = *reinterpret_cast<const s8b*>(qp + s * 512);

        const short* vp = Vf +
            ((((size_t)(b * 128 + ib) * 2) * 2 + hi) * 64 + l31) * 8;
        s8b vf[2][2];
#pragma unroll
        for (int s2 = 0; s2 < 2; ++s2)
#pragma unroll
            for (int nf = 0; nf < 2; ++nf)
                vf[s2][nf] = *reinterpret_cast<const s8b*>(
                    vp + s2 * 1024 + nf * 256);

        f32x4 li[4];
#pragma unroll
        for (int g = 0; g < 4; ++g)
            li[g] = *reinterpret_cast<const f32x4*>(lip + ib * 32 + 4 * hi + 8 * g);

        f32x16 sacc;
#pragma unroll
        for (int r = 0; r < 16; ++r) sacc[r] = 0.f;
#pragma unroll
        for (int s = 0; s < 4; ++s)
            sacc = __builtin_amdgcn_mfma_f32_32x32x16_bf16(qf[s], kf[s], sacc, 0, 0, 0);

        float p[16];
#pragma unroll
        for (int g = 0; g < 4; ++g)
#pragma unroll
            for (int q = 0; q < 4; ++q)
                p[g * 4 + q] = __expf(sacc[g * 4 + q]) * li[g][q];

        unsigned a0 = cvt_pk_bf16(p[0],  p[1]);
        unsigned a1 = cvt_pk_bf16(p[2],  p[3]);
        unsigned a2 = cvt_pk_bf16(p[4],  p[5]);
        unsigned a3 = cvt_pk_bf16(p[6],  p[7]);
        unsigned b0 = cvt_pk_bf16(p[8],  p[9]);
        unsigned b1 = cvt_pk_bf16(p[10], p[11]);
        unsigned b2 = cvt_pk_bf16(p[12], p[13]);
        unsigned b3 = cvt_pk_bf16(p[14], p[15]);
        permswap(a0, a2); permswap(a1, a3);
        permswap(b0, b2); permswap(b1, b3);
        PackAB pa0, pa1;
        pa0.u.x = a0; pa0.u.y = a1; pa0.u.z = a2; pa0.u.w = a3;
        pa1.u.x = b0; pa1.u.y = b1; pa1.u.z = b2; pa1.u.w = b3;

        acc0 = __builtin_amdgcn_mfma_f32_32x32x16_bf16(pa0.s, vf[0][0], acc0, 0, 0, 0);
        acc1 = __builtin_amdgcn_mfma_f32_32x32x16_bf16(pa0.s, vf[0][1], acc1, 0, 0, 0);
        acc0 = __builtin_amdgcn_mfma_f32_32x32x16_bf16(pa1.s, vf[1][0], acc0, 0, 0, 0);
        acc1 = __builtin_amdgcn_mfma_f32_32x32x16_bf16(pa1.s, vf[1][1], acc1, 0, 0, 0);
    }

    // tree combine across wr
    if (wr > 0) {
#pragma unroll
        for (int nf = 0; nf < 2; ++nf) {
            const f32x16& A = nf ? acc1 : acc0;
            int c = nf * 32 + l31;
#pragma unroll
            for (int g = 0; g < 4; ++g) {
                f32x4 v;
                v.x = A[g * 4 + 0]; v.y = A[g * 4 + 1];
                v.z = A[g * 4 + 2]; v.w = A[g * 4 + 3];
                *reinterpret_cast<f32x4*>(&red[wc][wr - 1][c][g * 8 + 4 * hi]) = v;
            }
        }
    }
    __syncthreads();
    if (wr == 0) {
#pragma unroll
        for (int nf = 0; nf < 2; ++nf) {
            const f32x16& A = nf ? acc1 : acc0;
            int c = nf * 32 + l31;
            const float sc = go[c] * rsqrtf(1.0f + EPS);
            const float bb = beo[c];
            size_t rowb = (((size_t)(b * 64 + c)) << 12) + jt * 64 + wc * 32;
#pragma unroll
            for (int g = 0; g < 4; ++g) {
                int jl = g * 8 + 4 * hi;
                f32x4 p0 = *reinterpret_cast<const f32x4*>(&red[wc][0][c][jl]);
                f32x4 p1 = *reinterpret_cast<const f32x4*>(&red[wc][1][c][jl]);
                f32x4 p2 = *reinterpret_cast<const f32x4*>(&red[wc][2][c][jl]);
                f32x4 xv = *reinterpret_cast<const f32x4*>(x + rowb + jl);
                f32x4 ov;
                ov.x = (A[g * 4 + 0] + p0.x + p1.x + p2.x + xv.x) * sc + bb;
                ov.y = (A[g * 4 + 1] + p0.y + p1.y + p2.y + xv.y) * sc + bb;
                ov.z = (A[g * 4 + 2] + p0.z + p1.z + p2.z + xv.z) * sc + bb;
                ov.w = (A[g * 4 + 3] + p0.w + p1.w + p2.w + xv.w) * sc + bb;
                *reinterpret_cast<f32x4*>(out + rowb + jl) = ov;
            }
        }
    }
}

extern "C" void kernel_launch(void* const* d_in, const int* in_sizes, int n_in,
                              void* d_out, int out_size, void* d_ws, size_t ws_size,
                              hipStream_t stream)
{
    (void)in_sizes; (void)n_in; (void)out_size; (void)ws_size;
    const float* x   = (const float*)d_in[0];
    const float* sal = (const float*)d_in[1];
    const float* wq  = (const float*)d_in[2];  const float* bq  = (const float*)d_in[3];
    const float* gq  = (const float*)d_in[4];  const float* beq = (const float*)d_in[5];
    const float* wk  = (const float*)d_in[6];  const float* bk  = (const float*)d_in[7];
    const float* gk  = (const float*)d_in[8];  const float* bek = (const float*)d_in[9];
    const float* wv  = (const float*)d_in[10]; const float* bv  = (const float*)d_in[11];
    const float* gv  = (const float*)d_in[12]; const float* bev = (const float*)d_in[13];
    const float* go  = (const float*)d_in[14]; const float* beo = (const float*)d_in[15];
    float* out = (float*)d_out;

    short* ws = (short*)d_ws;
    short* Qf = ws;                     // 2,097,152 bf16
    short* Kf = ws + 2097152;           // 2,097,152 bf16
    short* Vf = ws + 4194304;           // 2,097,152 bf16
    float* il = (float*)(ws + 6291456); // 32,768 f32

    qkv_kernel<<<512, 256, 0, stream>>>(x, sal, wq, bq, gq, beq,
                                        wk, bk, gk, bek, wv, bv, gv, bev,
                                        Qf, Kf, Vf);
    rowsum_kernel<<<1024, 256, 0, stream>>>(Qf, Kf, il);
    attnout_kernel<<<512, 512, 0, stream>>>(Qf, Kf, Vf, il, x, go, beo, out);
}